// Round 5
// baseline (2310.444 us; speedup 1.0000x reference)
//
#include <hip/hip_runtime.h>

#define NUSERS 100000
#define NITEMS 200000
#define EMBED  64
#define NTOT   300000
#define NNZE   2000000
#define BROWS  256                              // rows per bucket (bucket = row >> 8)
#define NBKT   ((NTOT + BROWS - 1) / BROWS)     // 1172
#define SPAD   68                               // LDS row stride in floats (64 + 4 pad -> spreads ds_add banks)
#define CHUNK  8192                             // edges per hist/place block

typedef unsigned long long u64;
typedef unsigned int       u32;

// ---------------------------------------------------------------------------
// 1) bucket histogram: LDS-aggregated counts, one global atomic per bucket/block
// ---------------------------------------------------------------------------
__global__ __launch_bounds__(1024)
void bucket_hist_kernel(const int* __restrict__ row, int* __restrict__ bcount) {
    __shared__ int s_cnt[NBKT];
    for (int i = threadIdx.x; i < NBKT; i += 1024) s_cnt[i] = 0;
    __syncthreads();
    const long base = (long)blockIdx.x * CHUNK;
    #pragma unroll
    for (int i = 0; i < CHUNK / 1024; ++i) {
        const long e = base + i * 1024 + threadIdx.x;
        if (e < NNZE) atomicAdd(&s_cnt[row[e] >> 8], 1);
    }
    __syncthreads();
    for (int i = threadIdx.x; i < NBKT; i += 1024) {
        const int c = s_cnt[i];
        if (c) atomicAdd(&bcount[i], c);
    }
}

// ---------------------------------------------------------------------------
// 2) exclusive scan of 1172 bucket counts -> bbase (+ total) and cursor copy
// ---------------------------------------------------------------------------
__global__ void scan_buckets_kernel(const int* __restrict__ bcount,
                                    int* __restrict__ bbase,
                                    int* __restrict__ cursor) {
    __shared__ int s[256];
    const int t = threadIdx.x;
    int carry = 0;
    for (int base = 0; base < NBKT; base += 256) {
        const int i = base + t;
        const int v = (i < NBKT) ? bcount[i] : 0;
        s[t] = v;
        __syncthreads();
        for (int off = 1; off < 256; off <<= 1) {
            const int tmp = (t >= off) ? s[t - off] : 0;
            __syncthreads();
            s[t] += tmp;
            __syncthreads();
        }
        if (i < NBKT) {
            const int ex = carry + s[t] - v;     // exclusive
            bbase[i]  = ex;
            cursor[i] = ex;
        }
        carry += s[255];
        __syncthreads();
    }
    if (t == 0) bbase[NBKT] = NNZE;
}

// ---------------------------------------------------------------------------
// 3) place: per-block LDS counts -> one cursor atomic per bucket -> direct
//    stores at base+rank. A block's stores per bucket form a ~220B window in
//    its own XCD's L2 -> writebacks merge (unlike the old global scatter).
//    Packed edge: hi32 = (row_local<<19)|col (8+19 bits), lo32 = val bits.
// ---------------------------------------------------------------------------
__global__ __launch_bounds__(1024)
void place_kernel(const float* __restrict__ vals,
                  const int*   __restrict__ row,
                  const int*   __restrict__ col,
                  int* __restrict__ cursor,
                  u64* __restrict__ staged) {
    __shared__ int s_cnt[NBKT];
    __shared__ int s_base[NBKT];
    for (int i = threadIdx.x; i < NBKT; i += 1024) s_cnt[i] = 0;
    __syncthreads();
    const long base = (long)blockIdx.x * CHUNK;
    #pragma unroll
    for (int i = 0; i < CHUNK / 1024; ++i) {
        const long e = base + i * 1024 + threadIdx.x;
        if (e < NNZE) atomicAdd(&s_cnt[row[e] >> 8], 1);
    }
    __syncthreads();
    for (int i = threadIdx.x; i < NBKT; i += 1024) {
        const int c = s_cnt[i];
        s_base[i] = c ? atomicAdd(&cursor[i], c) : 0;
        s_cnt[i]  = 0;                            // reuse as rank counter
    }
    __syncthreads();
    #pragma unroll
    for (int i = 0; i < CHUNK / 1024; ++i) {
        const long e = base + i * 1024 + threadIdx.x;
        if (e < NNZE) {
            const int r = row[e];
            const int b = r >> 8;
            const int rk = atomicAdd(&s_cnt[b], 1);
            const u64 hi = ((u64)(((u32)(r & 255) << 19) | (u32)col[e])) << 32;
            staged[s_base[b] + rk] = hi | (u64)__float_as_uint(vals[e]);
        }
    }
}

// ---------------------------------------------------------------------------
// SpMM with LDS accumulator: one block per 256-row bucket, no exact CSR, no
// global atomics. 16-lane groups: coalesced 256B gather of x[col], 4x
// ds_add_f32 into the padded LDS tile. Coalesced epilogue with fusions:
// MODE 0 (layer 1): gather from user/item; y = sum; acc = ego(r) + sum
// MODE 1 (layer 2): gather from x;         y = sum; acc += sum
// MODE 2 (layer 3): gather from x;         acc = (acc + sum) * 0.25
// ---------------------------------------------------------------------------
__device__ __forceinline__ const float* ego_ptr(const float* __restrict__ user,
                                                const float* __restrict__ item,
                                                int c) {
    return (c < NUSERS) ? (user + (long)c * EMBED)
                        : (item + (long)(c - NUSERS) * EMBED);
}

template <int MODE>
__global__ __launch_bounds__(1024)
void spmm_lds_kernel(const int* __restrict__ bbase,
                     const u64* __restrict__ staged,
                     const float* __restrict__ x,     // MODE 1,2
                     const float* __restrict__ user,  // MODE 0
                     const float* __restrict__ item,  // MODE 0
                     float* __restrict__ y,           // MODE 0,1
                     float* __restrict__ acc) {
    __shared__ float sacc[BROWS * SPAD];              // 256*68*4 = 68 KB
    for (int i = threadIdx.x; i < BROWS * SPAD; i += 1024) sacc[i] = 0.f;
    __syncthreads();

    const int b     = blockIdx.x;
    const int start = bbase[b];
    const int end   = bbase[b + 1];
    const int g = threadIdx.x >> 4;                   // 64 groups of 16
    const int q = threadIdx.x & 15;

    for (int j = start + g; j < end; j += 64) {
        const u64 w  = staged[j];
        const u32 hi = (u32)(w >> 32);
        const int c  = (int)(hi & 0x7FFFFu);
        const int rl = (int)(hi >> 19);
        const float v = __uint_as_float((u32)w);
        const float* xp = (MODE == 0) ? ego_ptr(user, item, c)
                                      : (x + (long)c * EMBED);
        const float4 xv = *reinterpret_cast<const float4*>(xp + q * 4);
        float* sp = &sacc[rl * SPAD + q * 4];
        atomicAdd(sp + 0, v * xv.x);
        atomicAdd(sp + 1, v * xv.y);
        atomicAdd(sp + 2, v * xv.z);
        atomicAdd(sp + 3, v * xv.w);
    }
    __syncthreads();

    // epilogue: 256 rows x 16 quads = 4096 float4 tasks
    for (int t = threadIdx.x; t < BROWS * 16; t += 1024) {
        const int lr = t >> 4;
        const int qq = t & 15;
        const int r  = b * BROWS + lr;
        if (r >= NTOT) continue;                      // only last bucket partial
        float4 a = *reinterpret_cast<const float4*>(&sacc[lr * SPAD + qq * 4]);
        const long o = (long)r * EMBED + qq * 4;
        if (MODE == 0) {
            *reinterpret_cast<float4*>(y + o) = a;
            const float4 e4 = *reinterpret_cast<const float4*>(ego_ptr(user, item, r) + qq * 4);
            a.x += e4.x; a.y += e4.y; a.z += e4.z; a.w += e4.w;
            *reinterpret_cast<float4*>(acc + o) = a;
        } else if (MODE == 1) {
            *reinterpret_cast<float4*>(y + o) = a;
            float4 old = *reinterpret_cast<float4*>(acc + o);
            old.x += a.x; old.y += a.y; old.z += a.z; old.w += a.w;
            *reinterpret_cast<float4*>(acc + o) = old;
        } else {
            float4 old = *reinterpret_cast<float4*>(acc + o);
            old.x = (old.x + a.x) * 0.25f;
            old.y = (old.y + a.y) * 0.25f;
            old.z = (old.z + a.z) * 0.25f;
            old.w = (old.w + a.w) * 0.25f;
            *reinterpret_cast<float4*>(acc + o) = old;
        }
    }
}

extern "C" void kernel_launch(void* const* d_in, const int* in_sizes, int n_in,
                              void* d_out, int out_size, void* d_ws, size_t ws_size,
                              hipStream_t stream) {
    const float* user = (const float*)d_in[0];
    const float* item = (const float*)d_in[1];
    const float* vals = (const float*)d_in[2];
    const int*   row  = (const int*)d_in[3];
    const int*   col  = (const int*)d_in[4];

    float* acc = (float*)d_out;

    // workspace layout (all offsets 8B-aligned)
    char* w = (char*)d_ws;
    float* x1     = (float*)w;  w += (size_t)NTOT * EMBED * 4;   // 76.8 MB
    float* x2     = (float*)w;  w += (size_t)NTOT * EMBED * 4;   // 76.8 MB
    u64*   staged = (u64*)w;    w += (size_t)NNZE * 8;           // 16 MB
    int*   bcount = (int*)w;    w += (size_t)NBKT * 4;
    int*   bbase  = (int*)w;    w += (size_t)(NBKT + 1) * 4;
    int*   cursor = (int*)w;    w += (size_t)NBKT * 4;

    const int EDGE_BLOCKS = (NNZE + CHUNK - 1) / CHUNK;          // 245

    // ---- build coarse-bucketed edge list (once; reused by all 3 layers) ----
    hipMemsetAsync(bcount, 0, (size_t)NBKT * 4, stream);
    bucket_hist_kernel<<<EDGE_BLOCKS, 1024, 0, stream>>>(row, bcount);
    scan_buckets_kernel<<<1, 256, 0, stream>>>(bcount, bbase, cursor);
    place_kernel<<<EDGE_BLOCKS, 1024, 0, stream>>>(vals, row, col, cursor, staged);

    // ---- 3 propagation layers (init fused into layer 1, scale into layer 3) ----
    spmm_lds_kernel<0><<<NBKT, 1024, 0, stream>>>(bbase, staged, nullptr, user, item, x1, acc);
    spmm_lds_kernel<1><<<NBKT, 1024, 0, stream>>>(bbase, staged, x1, nullptr, nullptr, x2, acc);
    spmm_lds_kernel<2><<<NBKT, 1024, 0, stream>>>(bbase, staged, x2, nullptr, nullptr, nullptr, acc);
}